// Round 3
// baseline (16040.018 us; speedup 1.0000x reference)
//
#include <hip/hip_runtime.h>
#include <math.h>

#define BB 64
#define TT 256
#define HH 512
#define TH (TT*HH)
#define BTH (BB*TT*HH)

typedef __attribute__((ext_vector_type(8))) short short8;
typedef __attribute__((ext_vector_type(4))) float f32x4;

__device__ __forceinline__ unsigned short f32_bf16(float f) {
    unsigned int u = __float_as_uint(f);
    return (unsigned short)((u + 0x7fffu + ((u >> 16) & 1u)) >> 16);
}

// ---- one-time: weights fp32 -> bf16 in MFMA-fragment-major layout ----
struct WConv {
    const float* src[10];
    int rs[10];
    int co[10];
    short* dst;
};
__global__ __launch_bounds__(256) void conv_w(WConv a) {
    const int rid = blockIdx.y;
    const int i = blockIdx.x * 256 + threadIdx.x;
    const int lane = i & 63;
    const int kc = (i >> 6) & 15;
    const int nt = i >> 10;
    const int n = nt * 16 + (lane & 15);
    const int kb = kc * 32 + (lane >> 4) * 8;
    const float* s = a.src[rid] + (size_t)n * a.rs[rid] + a.co[rid] + kb;
    float4 v0 = *(const float4*)s;
    float4 v1 = *(const float4*)(s + 4);
    short8 o;
    o[0]=f32_bf16(v0.x); o[1]=f32_bf16(v0.y); o[2]=f32_bf16(v0.z); o[3]=f32_bf16(v0.w);
    o[4]=f32_bf16(v1.x); o[5]=f32_bf16(v1.y); o[6]=f32_bf16(v1.z); o[7]=f32_bf16(v1.w);
    *(short8*)(a.dst + (size_t)rid * 1048576 + (size_t)i * 8) = o;
}

// ---- one-time: x fp32 -> bf16 fragment-major ----
struct XConv {
    const float* src[3];
    short* dst;
};
__global__ __launch_bounds__(256) void conv_x(XConv a) {
    const int l = blockIdx.y;
    const int i = blockIdx.x * 256 + threadIdx.x;
    const int lane = i & 63;
    const int kc = (i >> 6) & 15;
    const int btt = i >> 10;
    const int bt = btt & 3;
    const int t = btt >> 2;
    const int b = bt * 16 + (lane & 15);
    const int k = kc * 32 + (lane >> 4) * 8;
    const float* s = a.src[l] + ((size_t)b * TT + t) * HH + k;
    float4 v0 = *(const float4*)s;
    float4 v1 = *(const float4*)(s + 4);
    short8 o;
    o[0]=f32_bf16(v0.x); o[1]=f32_bf16(v0.y); o[2]=f32_bf16(v0.z); o[3]=f32_bf16(v0.w);
    o[4]=f32_bf16(v1.x); o[5]=f32_bf16(v1.y); o[6]=f32_bf16(v1.z); o[7]=f32_bf16(v1.w);
    *(short8*)(a.dst + (size_t)l * 8388608 + (size_t)i * 8) = o;
}

// ---- one-time: gx[l][t][bt][cb][q] = (x*d_bottom) @ W_ihx^T tile, fp32 in acc layout ----
struct GxArgs { const short* xreg; const short* wreg; const float* dx; float* gx; };
__global__ __launch_bounds__(256) void gx_kernel(GxArgs a) {
    const int xb = blockIdx.x;           // cb + 32*bt
    const int t = blockIdx.y;
    const int l = blockIdx.z;
    const int tid = threadIdx.x;
    const int lane = tid & 63;
    const int q = tid >> 6;
    const int cb = xb & 31, bt = xb >> 5;
    const float db = (l == 0) ? 1.f : a.dx[(bt*16 + (lane & 15))*768 + (l-1)*256 + t];
    const bool nz = db != 0.f;
    const short8 vz = {0,0,0,0,0,0,0,0};
    const int wx = (l == 0) ? 0 : ((l == 1) ? 3 : 7);
    const short* ap = a.xreg + (size_t)l*8388608 + (size_t)t*32768 + bt*8192 + lane*8;
    const short* wp = a.wreg + (size_t)wx*1048576 + (q*32 + cb)*8192 + lane*8;
    f32x4 acc = {0.f, 0.f, 0.f, 0.f};
    #pragma unroll
    for (int kk = 0; kk < 16; ++kk) {
        short8 av = *(const short8*)(ap + kk*512);
        short8 wv = *(const short8*)(wp + kk*512);
        av = nz ? av : vz;
        acc = __builtin_amdgcn_mfma_f32_16x16x32_bf16(av, wv, acc, 0, 0, 0);
    }
    const size_t tile = ((((size_t)l*256 + t)*4 + bt)*32 + cb)*4 + q;
    *(f32x4*)(a.gx + tile*256 + lane*4) = acc;
}

// ---- persistent sequential kernel ----
struct PersArgs {
    const short* wreg; const short* xreg; short* hreg; const float* gx;
    const float* dx; float* out; int* flags;
    const float* bih[3]; const float* bhh[3];
    int use_gx;
};

__global__ __launch_bounds__(512, 1) void persistent_kernel(PersArgs a) {
    const int bid = blockIdx.x;
    const int cb = bid & 31, bt = bid >> 5;
    const int tid = threadIdx.x;
    const int lane = tid & 63;
    const int wave = tid >> 6;
    const int q = wave & 3;
    const int half = wave >> 2;
    const int r16 = lane & 15;
    const int b_lane = bt * 16 + r16;

    __shared__ float g[8][16][17];
    __shared__ unsigned short hstage[256];

    // persistent per-tile state (epilogue threads tid<256 own one (b,c))
    float c_reg[3] = {0.f, 0.f, 0.f};
    float h_reg[3] = {0.f, 0.f, 0.f};
    float ebias[3][4];
    const int ec = cb * 16 + (tid & 15);
    const int eb = bt * 16 + (tid >> 4);
    if (tid < 256) {
        #pragma unroll
        for (int l = 0; l < 3; ++l)
            #pragma unroll
            for (int qq = 0; qq < 4; ++qq)
                ebias[l][qq] = a.bih[l][qq*512 + ec] + a.bhh[l][qq*512 + ec];
    }

    const int WX[3]  = {0, 3, 7};
    const int WTD[3] = {1, 5, 5};
    const int WBU[3] = {4, 4, 8};
    const int WHH[3] = {2, 6, 9};

    for (int t = 0; t < TT; ++t) {
        #pragma unroll
        for (int l = 0; l < 3; ++l) {
            const int stage = t*3 + l;
            const float dbv = (l == 0) ? 1.f : a.dx[b_lane*768 + (l-1)*256 + t];
            const float dv  = (t == 0) ? 0.f : a.dx[b_lane*768 + l*256 + (t-1)];

            f32x4 acc = {0.f, 0.f, 0.f, 0.f};
            if (a.use_gx && half == 0) {
                const size_t tile = ((((size_t)l*256 + t)*4 + bt)*32 + cb)*4 + q;
                acc = *(const f32x4*)(a.gx + tile*256 + lane*4);
            }

            auto do_seg = [&](const short* ab, const short* wb, float sc, const int* fl) {
                if (fl) {
                    for (;;) {
                        int v = 1;
                        if (lane < 32)
                            v = __hip_atomic_load(fl + lane, __ATOMIC_RELAXED, __HIP_MEMORY_SCOPE_AGENT);
                        if (__all(v != 0)) break;
                        __builtin_amdgcn_s_sleep(1);
                    }
                    __builtin_amdgcn_fence(__ATOMIC_ACQUIRE, "agent");
                }
                const bool nz = (sc != 0.f);
                const short8 vz = {0,0,0,0,0,0,0,0};
                const short* ap = ab + bt*8192 + half*4096 + lane*8;
                const short* wp = wb + (q*32 + cb)*8192 + half*4096 + lane*8;
                #pragma unroll
                for (int kk = 0; kk < 8; ++kk) {
                    short8 av = *(const short8*)(ap + kk*512);
                    short8 wv = *(const short8*)(wp + kk*512);
                    av = nz ? av : vz;
                    acc = __builtin_amdgcn_mfma_f32_16x16x32_bf16(av, wv, acc, 0, 0, 0);
                }
            };

            if (!a.use_gx)
                do_seg(a.xreg + (size_t)l*8388608 + (size_t)t*32768,
                       a.wreg + (size_t)WX[l]*1048576, (l == 0) ? 1.f : dbv, nullptr);
            if (t > 0) {
                do_seg(a.hreg + (size_t)(l*2 + ((t-1)&1))*32768,
                       a.wreg + (size_t)WHH[l]*1048576, 1.f,
                       a.flags + (((t-1)*3 + l)*4 + bt)*32);
                if (l < 2)
                    do_seg(a.hreg + (size_t)((l+1)*2 + ((t-1)&1))*32768,
                           a.wreg + (size_t)WTD[l]*1048576, dv,
                           a.flags + (((t-1)*3 + l+1)*4 + bt)*32);
            }
            if (l > 0)
                do_seg(a.hreg + (size_t)((l-1)*2 + (t&1))*32768,
                       a.wreg + (size_t)WBU[l]*1048576, dbv,
                       a.flags + ((t*3 + l-1)*4 + bt)*32);

            #pragma unroll
            for (int r = 0; r < 4; ++r)
                g[wave][(lane >> 4)*4 + r][r16] = acc[r];
            __syncthreads();

            if (tid < 256) {
                const int b_i = tid >> 4, c_i = tid & 15;
                float gi = g[0][b_i][c_i] + g[4][b_i][c_i] + ebias[l][0];
                float gf = g[1][b_i][c_i] + g[5][b_i][c_i] + ebias[l][1];
                float gg = g[2][b_i][c_i] + g[6][b_i][c_i] + ebias[l][2];
                float go = g[3][b_i][c_i] + g[7][b_i][c_i] + ebias[l][3];
                const float db2 = (l == 0) ? 1.f : a.dx[eb*768 + (l-1)*256 + t];
                const float d2  = (t == 0) ? 0.f : a.dx[eb*768 + l*256 + (t-1)];
                const float i_ = 1.f/(1.f + expf(-gi));
                const float f_ = 1.f/(1.f + expf(-gf));
                const float g_ = tanhf(gg);
                const float o_ = 1.f/(1.f + expf(-go));
                const float cc = c_reg[l] * (1.f - d2);
                const float cn_ = f_*cc + i_*g_;
                const float hn_ = o_*tanhf(cn_);
                const bool copy = (db2 + d2 == 0.f);
                const float h = copy ? h_reg[l] : hn_;
                c_reg[l] = copy ? cc : cn_;
                h_reg[l] = h;
                a.out[(size_t)l*BTH + (size_t)eb*TH + (size_t)t*HH + ec] = h;
                hstage[tid] = f32_bf16(h);
            }
            __syncthreads();

            if (tid < 128) {
                const int u = tid;
                const int j   = (2*u) & 7;
                const int b_i = (u >> 2) & 15;
                const int hi  = u >> 6;
                unsigned int lo16 = hstage[b_i*16 + hi*8 + j];
                unsigned int hi16 = hstage[b_i*16 + hi*8 + j + 1];
                unsigned int pack = lo16 | (hi16 << 16);
                unsigned int* dst = (unsigned int*)(a.hreg + (size_t)(l*2 + (t&1))*32768)
                                    + ((bt*16 + (cb >> 1))*256 + (cb & 1)*128 + u);
                __hip_atomic_store(dst, pack, __ATOMIC_RELAXED, __HIP_MEMORY_SCOPE_AGENT);
            }
            __syncthreads();

            if (tid == 0)
                __hip_atomic_store(a.flags + ((stage*4 + bt)*32 + cb), 1,
                                   __ATOMIC_RELEASE, __HIP_MEMORY_SCOPE_AGENT);
        }
    }
}

extern "C" void kernel_launch(void* const* d_in, const int* in_sizes, int n_in,
                              void* d_out, int out_size, void* d_ws, size_t ws_size,
                              hipStream_t stream) {
    const float* x[3]    = {(const float*)d_in[0], (const float*)d_in[1], (const float*)d_in[2]};
    const float* dx      = (const float*)d_in[3];
    const float* W_ih[3] = {(const float*)d_in[4], (const float*)d_in[8],  (const float*)d_in[12]};
    const float* W_hh[3] = {(const float*)d_in[5], (const float*)d_in[9],  (const float*)d_in[13]};
    const float* b_ih[3] = {(const float*)d_in[6], (const float*)d_in[10], (const float*)d_in[14]};
    const float* b_hh[3] = {(const float*)d_in[7], (const float*)d_in[11], (const float*)d_in[15]};
    float* out = (float*)d_out;

    // ws layout
    char* ws = (char*)d_ws;
    const size_t SZ_FLAGS = 393216;                 // 768*4*32 ints
    const size_t SZ_WREG  = 20971520;               // 10*2048*512 bf16
    const size_t SZ_XREG  = 50331648;               // 3*64*256*512 bf16
    const size_t SZ_HREG  = 393216;                 // 3*2*64*512 bf16
    const size_t SZ_GX    = 402653184;              // 3*256*4*32*4 tiles * 256 f32
    int*   flags = (int*)ws;
    short* wreg  = (short*)(ws + SZ_FLAGS);
    short* xreg  = (short*)(ws + SZ_FLAGS + SZ_WREG);
    short* hreg  = (short*)(ws + SZ_FLAGS + SZ_WREG + SZ_XREG);
    float* gx    = (float*)(ws + SZ_FLAGS + SZ_WREG + SZ_XREG + SZ_HREG);
    const int use_gx = (ws_size >= SZ_FLAGS + SZ_WREG + SZ_XREG + SZ_HREG + SZ_GX) ? 1 : 0;

    hipMemsetAsync(flags, 0, SZ_FLAGS, stream);

    {   // weight regions: [l0x,l0td,l0hh, l1x,l1bu,l1td,l1hh, l2x,l2bu,l2hh]
        WConv wa;
        const float* srcs[10] = {W_ih[0], W_ih[0], W_hh[0],
                                 W_ih[1], W_ih[1], W_ih[1], W_hh[1],
                                 W_ih[2], W_ih[2], W_hh[2]};
        const int rss[10] = {1024, 1024, 512, 1536, 1536, 1536, 512, 1024, 1024, 512};
        const int cos[10] = {0, 512, 0, 0, 512, 1024, 0, 0, 512, 0};
        for (int r = 0; r < 10; ++r) { wa.src[r] = srcs[r]; wa.rs[r] = rss[r]; wa.co[r] = cos[r]; }
        wa.dst = wreg;
        conv_w<<<dim3(512, 10), 256, 0, stream>>>(wa);
    }
    {
        XConv xa;
        xa.src[0] = x[0]; xa.src[1] = x[1]; xa.src[2] = x[2];
        xa.dst = xreg;
        conv_x<<<dim3(4096, 3), 256, 0, stream>>>(xa);
    }
    if (use_gx) {
        GxArgs ga;
        ga.xreg = xreg; ga.wreg = wreg; ga.dx = dx; ga.gx = gx;
        gx_kernel<<<dim3(128, 256, 3), 256, 0, stream>>>(ga);
    }

    PersArgs pa;
    pa.wreg = wreg; pa.xreg = xreg; pa.hreg = hreg; pa.gx = gx;
    pa.dx = dx; pa.out = out; pa.flags = flags; pa.use_gx = use_gx;
    for (int l = 0; l < 3; ++l) { pa.bih[l] = b_ih[l]; pa.bhh[l] = b_hh[l]; }
    persistent_kernel<<<dim3(128), 512, 0, stream>>>(pa);
}

// Round 4
// 6854.742 us; speedup vs baseline: 2.3400x; 2.3400x over previous
//
#include <hip/hip_runtime.h>
#include <math.h>

#define BB 64
#define TT 256
#define HH 512
#define TH (TT*HH)
#define BTH (BB*TT*HH)

typedef __attribute__((ext_vector_type(8))) short short8;
typedef __attribute__((ext_vector_type(4))) float f32x4;

__device__ __forceinline__ unsigned short f32_bf16(float f) {
    unsigned int u = __float_as_uint(f);
    return (unsigned short)((u + 0x7fffu + ((u >> 16) & 1u)) >> 16);
}

// ---- one-time: weights fp32 -> bf16 in MFMA-fragment-major layout ----
struct WConv {
    const float* src[10];
    int rs[10];
    int co[10];
    short* dst;
};
__global__ __launch_bounds__(256) void conv_w(WConv a) {
    const int rid = blockIdx.y;
    const int i = blockIdx.x * 256 + threadIdx.x;
    const int lane = i & 63;
    const int kc = (i >> 6) & 15;
    const int nt = i >> 10;
    const int n = nt * 16 + (lane & 15);
    const int kb = kc * 32 + (lane >> 4) * 8;
    const float* s = a.src[rid] + (size_t)n * a.rs[rid] + a.co[rid] + kb;
    float4 v0 = *(const float4*)s;
    float4 v1 = *(const float4*)(s + 4);
    short8 o;
    o[0]=f32_bf16(v0.x); o[1]=f32_bf16(v0.y); o[2]=f32_bf16(v0.z); o[3]=f32_bf16(v0.w);
    o[4]=f32_bf16(v1.x); o[5]=f32_bf16(v1.y); o[6]=f32_bf16(v1.z); o[7]=f32_bf16(v1.w);
    *(short8*)(a.dst + (size_t)rid * 1048576 + (size_t)i * 8) = o;
}

// ---- one-time: x fp32 -> bf16 fragment-major ----
struct XConv {
    const float* src[3];
    short* dst;
};
__global__ __launch_bounds__(256) void conv_x(XConv a) {
    const int l = blockIdx.y;
    const int i = blockIdx.x * 256 + threadIdx.x;
    const int lane = i & 63;
    const int kc = (i >> 6) & 15;
    const int btt = i >> 10;
    const int bt = btt & 3;
    const int t = btt >> 2;
    const int b = bt * 16 + (lane & 15);
    const int k = kc * 32 + (lane >> 4) * 8;
    const float* s = a.src[l] + ((size_t)b * TT + t) * HH + k;
    float4 v0 = *(const float4*)s;
    float4 v1 = *(const float4*)(s + 4);
    short8 o;
    o[0]=f32_bf16(v0.x); o[1]=f32_bf16(v0.y); o[2]=f32_bf16(v0.z); o[3]=f32_bf16(v0.w);
    o[4]=f32_bf16(v1.x); o[5]=f32_bf16(v1.y); o[6]=f32_bf16(v1.z); o[7]=f32_bf16(v1.w);
    *(short8*)(a.dst + (size_t)l * 8388608 + (size_t)i * 8) = o;
}

// ---- one-time: gx = (x*d_bottom) @ W_ihx^T tiles, fp32 in acc layout ----
struct GxArgs { const short* xreg; const short* wreg; const float* dx; float* gx; };
__global__ __launch_bounds__(256) void gx_kernel(GxArgs a) {
    const int xb = blockIdx.x;
    const int t = blockIdx.y;
    const int l = blockIdx.z;
    const int tid = threadIdx.x;
    const int lane = tid & 63;
    const int q = tid >> 6;
    const int cb = xb & 31, bt = xb >> 5;
    const float db = (l == 0) ? 1.f : a.dx[(bt*16 + (lane & 15))*768 + (l-1)*256 + t];
    const bool nz = db != 0.f;
    const short8 vz = {0,0,0,0,0,0,0,0};
    const int wx = (l == 0) ? 0 : ((l == 1) ? 3 : 7);
    const short* ap = a.xreg + (size_t)l*8388608 + (size_t)t*32768 + bt*8192 + lane*8;
    const short* wp = a.wreg + (size_t)wx*1048576 + (q*32 + cb)*8192 + lane*8;
    f32x4 acc = {0.f, 0.f, 0.f, 0.f};
    #pragma unroll
    for (int kk = 0; kk < 16; ++kk) {
        short8 av = *(const short8*)(ap + kk*512);
        short8 wv = *(const short8*)(wp + kk*512);
        av = nz ? av : vz;
        acc = __builtin_amdgcn_mfma_f32_16x16x32_bf16(av, wv, acc, 0, 0, 0);
    }
    const size_t tile = ((((size_t)l*256 + t)*4 + bt)*32 + cb)*4 + q;
    *(f32x4*)(a.gx + tile*256 + lane*4) = acc;
}

// ---- persistent, layer-parallel sequential kernel ----
struct PersArgs {
    const short* wreg; const short* xreg; short* hreg; const float* gx;
    const float* dx; float* out; int* flags;
    const float* bih[3]; const float* bhh[3];
    int use_gx;
};

__global__ __launch_bounds__(512, 4) void persistent_kernel(PersArgs a) {
    const int bid = blockIdx.x;
    const int l = bid >> 7;              // 0..2 : fixed layer per block
    const int r = bid & 127;
    const int cb = r & 31, bt = r >> 5;
    const int tid = threadIdx.x;
    const int lane = tid & 63;
    const int wave = tid >> 6;
    const int q = wave & 3;
    const int half = wave >> 2;
    const int r16 = lane & 15;
    const int b_lane = bt * 16 + r16;

    __shared__ float g[8][16][17];
    __shared__ unsigned short hstage[256];

    float c_reg = 0.f, h_reg = 0.f;
    float eb0 = 0.f, eb1 = 0.f, eb2 = 0.f, eb3 = 0.f;
    const int ec = cb * 16 + (tid & 15);
    const int ebrow = bt * 16 + (tid >> 4);
    if (tid < 256) {
        eb0 = a.bih[l][ec]        + a.bhh[l][ec];
        eb1 = a.bih[l][512 + ec]  + a.bhh[l][512 + ec];
        eb2 = a.bih[l][1024 + ec] + a.bhh[l][1024 + ec];
        eb3 = a.bih[l][1536 + ec] + a.bhh[l][1536 + ec];
    }

    const int WX[3]  = {0, 3, 7};
    const int WTD[3] = {1, 5, 5};
    const int WBU[3] = {4, 4, 8};
    const int WHH[3] = {2, 6, 9};
    const int woff = (q*32 + cb)*8192 + half*4096 + lane*8;
    const short* whh = a.wreg + (size_t)WHH[l]*1048576 + woff;
    const short* wtd = a.wreg + (size_t)WTD[l]*1048576 + woff;
    const short* wbu = a.wreg + (size_t)WBU[l]*1048576 + woff;
    const short* wx  = a.wreg + (size_t)WX[l]*1048576 + woff;
    const int hoff = bt*8192 + half*4096 + lane*8;
    const short8 vz = {0,0,0,0,0,0,0,0};

    for (int t = 0; t < TT; ++t) {
        const int stage = t*3 + l;
        f32x4 acc = {0.f, 0.f, 0.f, 0.f};
        f32x4 gxv = {0.f, 0.f, 0.f, 0.f};
        if (a.use_gx && half == 0) {     // issue early: HBM latency hides under polls
            const size_t tile = ((((size_t)l*256 + t)*4 + bt)*32 + cb)*4 + q;
            gxv = *(const f32x4*)(a.gx + tile*256 + lane*4);
        }
        const float dbv = (l == 0) ? 1.f : a.dx[b_lane*768 + (l-1)*256 + t];
        const float dv  = (t == 0) ? 0.f : a.dx[b_lane*768 + l*256 + (t-1)];

        // ---- phase 1: t-1 dependencies (hh, td) ----
        if (t > 0) {
            if (wave == 0) {
                const int* f1 = a.flags + (((t-1)*3 + l)*4 + bt)*32;
                for (;;) {
                    int v = 1;
                    if (lane < 32) v = __hip_atomic_load(f1 + lane, __ATOMIC_RELAXED, __HIP_MEMORY_SCOPE_AGENT);
                    if (__all(v != 0)) break;
                    __builtin_amdgcn_s_sleep(2);
                }
                if (l < 2) {
                    const int* f2 = a.flags + (((t-1)*3 + l + 1)*4 + bt)*32;
                    for (;;) {
                        int v = 1;
                        if (lane < 32) v = __hip_atomic_load(f2 + lane, __ATOMIC_RELAXED, __HIP_MEMORY_SCOPE_AGENT);
                        if (__all(v != 0)) break;
                        __builtin_amdgcn_s_sleep(2);
                    }
                }
                __builtin_amdgcn_fence(__ATOMIC_ACQUIRE, "agent");
            }
            __syncthreads();
            {   // recurrent hh
                const short* ap = a.hreg + (size_t)(l*2 + ((t-1)&1))*32768 + hoff;
                #pragma unroll
                for (int kk = 0; kk < 8; ++kk) {
                    short8 av = *(const short8*)(ap + kk*512);
                    short8 wv = *(const short8*)(whh + kk*512);
                    acc = __builtin_amdgcn_mfma_f32_16x16x32_bf16(av, wv, acc, 0, 0, 0);
                }
            }
            if (l < 2) {  // top-down
                const bool nz = dv != 0.f;
                const short* ap = a.hreg + (size_t)((l+1)*2 + ((t-1)&1))*32768 + hoff;
                #pragma unroll
                for (int kk = 0; kk < 8; ++kk) {
                    short8 av = *(const short8*)(ap + kk*512);
                    short8 wv = *(const short8*)(wtd + kk*512);
                    av = nz ? av : vz;
                    acc = __builtin_amdgcn_mfma_f32_16x16x32_bf16(av, wv, acc, 0, 0, 0);
                }
            }
        }
        if (!a.use_gx) {  // x segment fallback (no dependency)
            const float sc = (l == 0) ? 1.f : dbv;
            const bool nz = sc != 0.f;
            const short* ap = a.xreg + (size_t)l*8388608 + (size_t)t*32768 + hoff;
            #pragma unroll
            for (int kk = 0; kk < 8; ++kk) {
                short8 av = *(const short8*)(ap + kk*512);
                short8 wv = *(const short8*)(wx + kk*512);
                av = nz ? av : vz;
                acc = __builtin_amdgcn_mfma_f32_16x16x32_bf16(av, wv, acc, 0, 0, 0);
            }
        }
        // ---- phase 2: same-t bottom-up dependency ----
        if (l > 0) {
            if (wave == 0) {
                const int* f3 = a.flags + ((t*3 + l - 1)*4 + bt)*32;
                for (;;) {
                    int v = 1;
                    if (lane < 32) v = __hip_atomic_load(f3 + lane, __ATOMIC_RELAXED, __HIP_MEMORY_SCOPE_AGENT);
                    if (__all(v != 0)) break;
                    __builtin_amdgcn_s_sleep(2);
                }
                __builtin_amdgcn_fence(__ATOMIC_ACQUIRE, "agent");
            }
            __syncthreads();
            const bool nz = dbv != 0.f;
            const short* ap = a.hreg + (size_t)((l-1)*2 + (t&1))*32768 + hoff;
            #pragma unroll
            for (int kk = 0; kk < 8; ++kk) {
                short8 av = *(const short8*)(ap + kk*512);
                short8 wv = *(const short8*)(wbu + kk*512);
                av = nz ? av : vz;
                acc = __builtin_amdgcn_mfma_f32_16x16x32_bf16(av, wv, acc, 0, 0, 0);
            }
        }

        #pragma unroll
        for (int rr = 0; rr < 4; ++rr)
            g[wave][(lane >> 4)*4 + rr][r16] = acc[rr] + gxv[rr];
        __syncthreads();

        float hval = 0.f;
        if (tid < 256) {
            const int b_i = tid >> 4, c_i = tid & 15;
            float gi = g[0][b_i][c_i] + g[4][b_i][c_i] + eb0;
            float gf = g[1][b_i][c_i] + g[5][b_i][c_i] + eb1;
            float gg = g[2][b_i][c_i] + g[6][b_i][c_i] + eb2;
            float go = g[3][b_i][c_i] + g[7][b_i][c_i] + eb3;
            const float db2 = (l == 0) ? 1.f : a.dx[ebrow*768 + (l-1)*256 + t];
            const float d2  = (t == 0) ? 0.f : a.dx[ebrow*768 + l*256 + (t-1)];
            const float i_ = 1.f/(1.f + expf(-gi));
            const float f_ = 1.f/(1.f + expf(-gf));
            const float g_ = tanhf(gg);
            const float o_ = 1.f/(1.f + expf(-go));
            const float cc = c_reg * (1.f - d2);
            const float cn_ = f_*cc + i_*g_;
            const float hn_ = o_*tanhf(cn_);
            const bool copy = (db2 + d2 == 0.f);
            hval = copy ? h_reg : hn_;
            c_reg = copy ? cc : cn_;
            h_reg = hval;
            hstage[tid] = f32_bf16(hval);
        }
        __syncthreads();
        if (tid < 128) {   // pack h tile -> bf16 ring slot (fragment-major)
            const int u = tid;
            const int j   = (2*u) & 7;
            const int b_i = (u >> 2) & 15;
            const int hi  = u >> 6;
            unsigned int lo16 = hstage[b_i*16 + hi*8 + j];
            unsigned int hi16 = hstage[b_i*16 + hi*8 + j + 1];
            unsigned int pack = lo16 | (hi16 << 16);
            unsigned int* dst = (unsigned int*)(a.hreg + (size_t)(l*2 + (t&1))*32768)
                                + ((bt*16 + (cb >> 1))*256 + (cb & 1)*128 + u);
            __hip_atomic_store(dst, pack, __ATOMIC_RELAXED, __HIP_MEMORY_SCOPE_AGENT);
        }
        __syncthreads();   // drains hreg stores (waitcnt before barrier)
        if (tid == 0)
            __hip_atomic_store(a.flags + ((stage*4 + bt)*32 + cb), 1,
                               __ATOMIC_RELEASE, __HIP_MEMORY_SCOPE_AGENT);
        // HBM output store AFTER the flag -> off the critical path
        if (tid < 256)
            a.out[(size_t)l*BTH + (size_t)ebrow*TH + (size_t)t*HH + ec] = hval;
    }
}

extern "C" void kernel_launch(void* const* d_in, const int* in_sizes, int n_in,
                              void* d_out, int out_size, void* d_ws, size_t ws_size,
                              hipStream_t stream) {
    const float* x[3]    = {(const float*)d_in[0], (const float*)d_in[1], (const float*)d_in[2]};
    const float* dx      = (const float*)d_in[3];
    const float* W_ih[3] = {(const float*)d_in[4], (const float*)d_in[8],  (const float*)d_in[12]};
    const float* W_hh[3] = {(const float*)d_in[5], (const float*)d_in[9],  (const float*)d_in[13]};
    const float* b_ih[3] = {(const float*)d_in[6], (const float*)d_in[10], (const float*)d_in[14]};
    const float* b_hh[3] = {(const float*)d_in[7], (const float*)d_in[11], (const float*)d_in[15]};
    float* out = (float*)d_out;

    char* ws = (char*)d_ws;
    const size_t SZ_FLAGS = 393216;                 // 768*4*32 ints
    const size_t SZ_WREG  = 20971520;               // 10*2048*512 bf16
    const size_t SZ_XREG  = 50331648;               // 3*64*256*512 bf16
    const size_t SZ_HREG  = 393216;                 // 3*2*64*512 bf16
    const size_t SZ_GX    = 402653184;              // 3*256*128 tiles * 256 f32
    int*   flags = (int*)ws;
    short* wreg  = (short*)(ws + SZ_FLAGS);
    short* xreg  = (short*)(ws + SZ_FLAGS + SZ_WREG);
    short* hreg  = (short*)(ws + SZ_FLAGS + SZ_WREG + SZ_XREG);
    float* gx    = (float*)(ws + SZ_FLAGS + SZ_WREG + SZ_XREG + SZ_HREG);
    const int use_gx = (ws_size >= SZ_FLAGS + SZ_WREG + SZ_XREG + SZ_HREG + SZ_GX) ? 1 : 0;

    hipMemsetAsync(flags, 0, SZ_FLAGS, stream);

    {
        WConv wa;
        const float* srcs[10] = {W_ih[0], W_ih[0], W_hh[0],
                                 W_ih[1], W_ih[1], W_ih[1], W_hh[1],
                                 W_ih[2], W_ih[2], W_hh[2]};
        const int rss[10] = {1024, 1024, 512, 1536, 1536, 1536, 512, 1024, 1024, 512};
        const int cos[10] = {0, 512, 0, 0, 512, 1024, 0, 0, 512, 0};
        for (int r = 0; r < 10; ++r) { wa.src[r] = srcs[r]; wa.rs[r] = rss[r]; wa.co[r] = cos[r]; }
        wa.dst = wreg;
        conv_w<<<dim3(512, 10), 256, 0, stream>>>(wa);
    }
    {
        XConv xa;
        xa.src[0] = x[0]; xa.src[1] = x[1]; xa.src[2] = x[2];
        xa.dst = xreg;
        conv_x<<<dim3(4096, 3), 256, 0, stream>>>(xa);
    }
    if (use_gx) {
        GxArgs ga;
        ga.xreg = xreg; ga.wreg = wreg; ga.dx = dx; ga.gx = gx;
        gx_kernel<<<dim3(128, 256, 3), 256, 0, stream>>>(ga);
    }

    PersArgs pa;
    pa.wreg = wreg; pa.xreg = xreg; pa.hreg = hreg; pa.gx = gx;
    pa.dx = dx; pa.out = out; pa.flags = flags; pa.use_gx = use_gx;
    for (int l = 0; l < 3; ++l) { pa.bih[l] = b_ih[l]; pa.bhh[l] = b_hh[l]; }
    persistent_kernel<<<dim3(384), 512, 0, stream>>>(pa);
}